// Round 10
// baseline (315.845 us; speedup 1.0000x reference)
//
#include <hip/hip_runtime.h>
#include <hip/hip_bf16.h>

typedef __hip_bfloat16 bf16;
typedef unsigned short u16;
typedef __attribute__((ext_vector_type(8))) short short8;
typedef __attribute__((ext_vector_type(4))) float f32x4;

#define D_MODEL 1024
#define NUM_HEADS 16
#define DEPTH 64
#define BATCH 4
#define SEQ 1024
#define BS (BATCH * SEQ)

__device__ __forceinline__ float ldDyn(const void* p, size_t i, int isbf) {
  return isbf ? __bfloat162float(((const bf16*)p)[i]) : ((const float*)p)[i];
}
__device__ __forceinline__ u16 f2bf(float f) {
  bf16 h = __float2bfloat16(f);
  return *(u16*)&h;
}
// async global->LDS, 16B per lane; LDS dest = wave-uniform base + lane*16
__device__ __forceinline__ void gl2lds16(const void* g, void* l) {
  __builtin_amdgcn_global_load_lds((const __attribute__((address_space(1))) unsigned int*)g,
                                   (__attribute__((address_space(3))) unsigned int*)l, 16, 0, 0);
}

// Detect input dtype: bf16 (1) vs fp32 (0). See round-1 notes.
__global__ void detect_kernel(const u16* __restrict__ q, int* __restrict__ flag) {
  if (threadIdx.x == 0 && blockIdx.x == 0) {
    int sane = 0;
    for (int i = 0; i < 64; ++i) {
      u16 h = q[2 * i];
      int e = (h >> 7) & 0xFF;
      if (e >= 100 && e <= 150) ++sane;
    }
    *flag = (sane >= 48) ? 1 : 0;
  }
}

// Batched 1024x1024 transpose (+convert to bf16): out[z][n][k] = in[z][k][n].
__global__ __launch_bounds__(256) void transpose_w(
    const void* W0, const void* W1, const void* W2, const void* W3, const void* W4,
    const void* W5, u16* __restrict__ WT, const int* __restrict__ flagp) {
  const int isbf = *flagp;
  const int z = blockIdx.z;
  const void* W = (z == 0) ? W0 : (z == 1) ? W1 : (z == 2) ? W2
                 : (z == 3) ? W3 : (z == 4) ? W4 : W5;
  u16* out = WT + (size_t)z * D_MODEL * D_MODEL;
  __shared__ u16 tile[32][33];
  const int t = threadIdx.x;
  const int tx = t & 31, ty = t >> 5;
  const int r0 = blockIdx.y * 32, c0 = blockIdx.x * 32;
#pragma unroll
  for (int i = 0; i < 4; ++i) {
    size_t gi = (size_t)(r0 + ty + 8 * i) * D_MODEL + c0 + tx;
    tile[ty + 8 * i][tx] = isbf ? ((const u16*)W)[gi] : f2bf(((const float*)W)[gi]);
  }
  __syncthreads();
#pragma unroll
  for (int i = 0; i < 4; ++i)
    out[(size_t)(c0 + ty + 8 * i) * D_MODEL + r0 + tx] = tile[tx][ty + 8 * i];
}

struct GArgs {
  const void* A[5];
  const u16* W[5];
  const void* bias[5];
  void* C[5];
  int Mr[5];
  int om[5];
};

// C(M,1024) = A(M,1024) @ W + bias, W passed transposed (WT, bf16).
// Double-buffered async global_load_lds pipeline (flash-style, one barrier per
// k-iter): tile k+1's DMA issues BEFORE computing tile k, so the vmcnt drain at
// the barrier is overlapped by compute (r9: 2-barrier shape left MfmaUtil at
// 11% -- latency-bound, not BW-bound; FETCH was already fixed by XCD swizzle).
// ABF: compile-time "A is bf16". GATE: early-exit unless runtime flag matches.
// omode: 0 = final out (dtype per flag); 1 = bf16; 2 = bf16 transposed [N][M].
template <int ABF, int GATE>
__global__ __launch_bounds__(256) void gemm_mfma(GArgs ga, const int* __restrict__ flagp) {
  const int isbf = *flagp;
  if (GATE && isbf != ABF) return;
  const int z = blockIdx.z;
  const int M = ga.Mr[z];
  // XCD swizzle: grid (8,32,z). lin%8 == rowb%8 for every col-block of rowb.
  const int lin = blockIdx.x + 8 * blockIdx.y;  // 0..255
  const int xcd = lin & 7;
  const int loc = lin >> 3;                     // 0..31
  const int rowb = (loc & 3) * 8 + xcd;         // 0..31
  const int colb = loc >> 2;                    // 0..7
  const int row0 = rowb * 128, col0 = colb * 128;
  if (row0 >= M) return;
  const void* A = ga.A[z];
  const u16* WT = ga.W[z];
  const void* bias = ga.bias[z];
  void* C = ga.C[z];
  const int omode = ga.om[z];

  __shared__ short As[2][128][32];
  __shared__ short Bs[2][128][32];
  const int t = threadIdx.x;
  const int wave = t >> 6, lane = t & 63;
  const int quad = lane >> 4, c16 = lane & 15;
  const int wrow = wave >> 1, wcol = wave & 1;

  f32x4 acc[4][4];
#pragma unroll
  for (int mt = 0; mt < 4; ++mt)
#pragma unroll
    for (int nt = 0; nt < 4; ++nt) acc[mt][nt] = {0.f, 0.f, 0.f, 0.f};

#define G_STAGE(K0, BUF)                                                                  \
  {                                                                                       \
    _Pragma("unroll") for (int i = 0; i < 2; ++i) {                                       \
      int L = t + 256 * i;                                                                \
      int r = L >> 2;                                                                     \
      int kc = (L & 3) ^ (r & 3); /* swizzle on the global side; LDS dest linear */       \
      gl2lds16(WT + (size_t)(col0 + r) * 1024 + (K0) + kc * 8,                            \
               (char*)&Bs[BUF][0][0] + (size_t)(i * 256 + wave * 64) * 16);               \
      if (ABF) {                                                                          \
        gl2lds16((const u16*)A + (size_t)(row0 + r) * 1024 + (K0) + kc * 8,               \
                 (char*)&As[BUF][0][0] + (size_t)(i * 256 + wave * 64) * 16);             \
      } else {                                                                            \
        const float* af = (const float*)A + (size_t)(row0 + r) * 1024 + (K0) + kc * 8;    \
        float4 lo = *(const float4*)af;                                                   \
        float4 hi = *(const float4*)(af + 4);                                             \
        short8 v;                                                                         \
        u16* pv = (u16*)&v;                                                               \
        pv[0] = f2bf(lo.x); pv[1] = f2bf(lo.y); pv[2] = f2bf(lo.z); pv[3] = f2bf(lo.w);   \
        pv[4] = f2bf(hi.x); pv[5] = f2bf(hi.y); pv[6] = f2bf(hi.z); pv[7] = f2bf(hi.w);   \
        *(short8*)&As[BUF][r][(L & 3) * 8] = v;                                           \
      }                                                                                   \
    }                                                                                     \
  }

  // prologue: stage tile 0, drain
  G_STAGE(0, 0);
  __syncthreads();

  for (int k0 = 0; k0 < 1024; k0 += 32) {
    const int cur = (k0 >> 5) & 1, nxt = cur ^ 1;
    if (k0 + 32 < 1024) G_STAGE(k0 + 32, nxt);  // DMA for next tile, in flight during compute

    short8 af[4], bfv[4];
#pragma unroll
    for (int mt = 0; mt < 4; ++mt)
      af[mt] = *(const short8*)&As[cur][wrow * 64 + mt * 16 + c16][((quad ^ (c16 & 3)) * 8)];
#pragma unroll
    for (int nt = 0; nt < 4; ++nt)
      bfv[nt] = *(const short8*)&Bs[cur][wcol * 64 + nt * 16 + c16][((quad ^ (c16 & 3)) * 8)];
#pragma unroll
    for (int nt = 0; nt < 4; ++nt)
#pragma unroll
      for (int mt = 0; mt < 4; ++mt)
        acc[mt][nt] = __builtin_amdgcn_mfma_f32_16x16x32_bf16(af[mt], bfv[nt], acc[mt][nt], 0, 0, 0);
    __syncthreads();  // drains next-tile DMA (overlapped by the MFMAs above); guards reuse
  }
#undef G_STAGE

#pragma unroll
  for (int nt = 0; nt < 4; ++nt) {
    int gc = col0 + wcol * 64 + nt * 16 + c16;
    float bb = ldDyn(bias, gc, isbf);
#pragma unroll
    for (int mt = 0; mt < 4; ++mt) {
      int gr0 = row0 + wrow * 64 + mt * 16 + quad * 4;
      if (omode == 2) {
        __attribute__((ext_vector_type(4))) short pk;
#pragma unroll
        for (int r = 0; r < 4; ++r) pk[r] = (short)f2bf(acc[mt][nt][r] + bb);
        *(__attribute__((ext_vector_type(4))) short*)&((u16*)C)[(size_t)gc * M + gr0] = pk;
      } else if (omode == 1 || isbf) {
#pragma unroll
        for (int r = 0; r < 4; ++r)
          ((bf16*)C)[(size_t)(gr0 + r) * 1024 + gc] = __float2bfloat16(acc[mt][nt][r] + bb);
      } else {
#pragma unroll
        for (int r = 0; r < 4; ++r)
          ((float*)C)[(size_t)(gr0 + r) * 1024 + gc] = acc[mt][nt][r] + bb;
      }
    }
  }
}

// Flash attention, m97-style: double-buffered async global_load_lds staging of
// the K-hat (64x128) and V^T (64x64) tiles; one barrier per kt drains the DMA.
// q-tile 128 (4 waves x 2 strips), K/V frags = swizzled ds_read_b128.
// Fixed-shift softmax (exact here); per-wave P roundtrip (8 KB).
__global__ __launch_bounds__(256) void flash_attn(
    const bf16* __restrict__ Qc, const bf16* __restrict__ Kc, const bf16* __restrict__ VcT,
    const bf16* __restrict__ Qp, const bf16* __restrict__ Kp,
    const void* __restrict__ th_cc, const void* __restrict__ th_co,
    const void* __restrict__ th_oc, bf16* __restrict__ O, const int* __restrict__ flagp) {
  const int isbf = *flagp;
  const int h = blockIdx.x, b = blockIdx.y, qt = blockIdx.z;
  const int t = threadIdx.x, wave = t >> 6, lane = t & 63;
  const int quad = lane >> 4, c16 = lane & 15;

  __shared__ short Kt[2][64][128];  // [buf][key][aug dims], slot kc holds chunk kc^(key&15)
  __shared__ short Vt[2][64][64];   // [buf][d][keys], slot kc holds chunk kc^(d&7)
  __shared__ short Pt[4][16][64];   // per-wave P strip (mt-sequential), swizzled ^ (row&7)

  const float tcc = ldDyn(th_cc, h, isbf);
  const float tco = ldDyn(th_co, h, isbf);
  const float toc = ldDyn(th_oc, h, isbf);

  const bf16* kcb = Kc + (size_t)b * SEQ * 1024 + h * 64;
  const bf16* kpb = Kp + h * 64;
  const bf16* vtb = VcT + (size_t)(h * 64) * BS + (size_t)b * SEQ;

  // staging lane roles
  const int rwK = lane >> 4, kcK = lane & 15;  // K-hat: 4 rows/inst, 16 chunks/row
  const int rwV = lane >> 3, kcV = lane & 7;   // V^T : 8 rows/inst,  8 chunks/row

#define STAGE_K(KT2, BUF)                                                              \
  {                                                                                    \
    _Pragma("unroll") for (int i = 0; i < 4; ++i) {                                    \
      int r = wave * 16 + i * 4 + rwK;                                                 \
      int c = kcK ^ (r & 15);                                                          \
      int key = (KT2)*64 + r;                                                          \
      const bf16* src = (c < 8) ? kcb + (size_t)key * 1024 + c * 8                     \
                                : kpb + (size_t)key * 1024 + c * 8 - 64;               \
      gl2lds16(src, &Kt[BUF][wave * 16 + i * 4][0]);                                   \
    }                                                                                  \
  }
#define STAGE_V(KT2, BUF)                                                              \
  {                                                                                    \
    _Pragma("unroll") for (int j = 0; j < 2; ++j) {                                    \
      int d = wave * 16 + j * 8 + rwV;                                                 \
      int c = kcV ^ (d & 7);                                                           \
      gl2lds16(vtb + (size_t)d * BS + (KT2)*64 + c * 8, &Vt[BUF][wave * 16 + j * 8][0]); \
    }                                                                                  \
  }

  // Q A-frags (register-resident, 2 strips)
  short8 qf[2][4];
#pragma unroll
  for (int mt = 0; mt < 2; ++mt) {
    int qrow = qt * 128 + wave * 32 + mt * 16 + c16;
#pragma unroll
    for (int ks = 0; ks < 4; ++ks) {
      int d = ks * 32 + quad * 8;
      const bf16* src = (d < 64) ? Qc + ((size_t)(b * SEQ + qrow)) * 1024 + h * 64 + d
                                 : Qp + (size_t)qrow * 1024 + h * 64 + (d - 64);
      qf[mt][ks] = *(const short8*)src;
    }
    if (qrow == 0) {  // zero pos-half for q==0 (theta replaces pos there)
      qf[mt][2] = (short8)0;
      qf[mt][3] = (short8)0;
    }
  }

  f32x4 accO[2][4];
#pragma unroll
  for (int mt = 0; mt < 2; ++mt)
#pragma unroll
    for (int nt = 0; nt < 4; ++nt) accO[mt][nt] = {0.f, 0.f, 0.f, 0.f};
  float lrow[2][4] = {{0.f, 0.f, 0.f, 0.f}, {0.f, 0.f, 0.f, 0.f}};

  // prologue: stage tile 0, drain, zero key-0 pos-half (theta replaces it)
  STAGE_K(0, 0);
  STAGE_V(0, 0);
  __syncthreads();
  if (t < 8) *(short8*)&Kt[0][0][64 + t * 8] = (short8)0;  // row0 swizzle = identity
  __syncthreads();

  for (int kt = 0; kt < 16; ++kt) {
    const int cur = kt & 1, nxt = cur ^ 1;
    if (kt < 15) {
      STAGE_K(kt + 1, nxt);
      STAGE_V(kt + 1, nxt);
    }

    // ---- S = Q-hat (32x128) x K-hat^T from LDS ----
    f32x4 accS[2][4];
#pragma unroll
    for (int mt = 0; mt < 2; ++mt)
#pragma unroll
      for (int nt = 0; nt < 4; ++nt) accS[mt][nt] = {0.f, 0.f, 0.f, 0.f};
#pragma unroll
    for (int nt = 0; nt < 4; ++nt)
#pragma unroll
      for (int ks = 0; ks < 4; ++ks) {
        short8 kf = *(const short8*)&Kt[cur][nt * 16 + c16][((ks * 4 + quad) ^ c16) * 8];
#pragma unroll
        for (int mt = 0; mt < 2; ++mt)
          accS[mt][nt] = __builtin_amdgcn_mfma_f32_16x16x32_bf16(qf[mt][ks], kf, accS[mt][nt], 0, 0, 0);
      }

    // ---- V frags to registers (reused by both strips) ----
    short8 vbreg[2][4];
#pragma unroll
    for (int ks2 = 0; ks2 < 2; ++ks2)
#pragma unroll
      for (int nt = 0; nt < 4; ++nt)
        vbreg[ks2][nt] =
            *(const short8*)&Vt[cur][nt * 16 + c16][(((ks2 * 4 + quad) ^ (c16 & 7)) & 7) * 8];

    // ---- per strip: softmax-lite + P roundtrip + PV ----
#pragma unroll
    for (int mt = 0; mt < 2; ++mt) {
      float s[4][4];
#pragma unroll
      for (int nt = 0; nt < 4; ++nt)
#pragma unroll
        for (int r = 0; r < 4; ++r) s[nt][r] = accS[mt][nt][r] * 0.125f;

      if (kt == 0 || (qt == 0 && wave == 0 && mt == 0)) {
#pragma unroll
        for (int nt = 0; nt < 4; ++nt)
#pragma unroll
          for (int r = 0; r < 4; ++r) {
            int kcol = kt * 64 + nt * 16 + c16;
            int qrow = qt * 128 + wave * 32 + mt * 16 + quad * 4 + r;
            float add = 0.f;
            if (qrow == 0 && kcol == 0) add = tcc;
            else if (qrow == 0) add = tco;
            else if (kcol == 0) add = toc;
            s[nt][r] += add * 0.125f;
          }
      }
#pragma unroll
      for (int nt = 0; nt < 4; ++nt)
#pragma unroll
        for (int r = 0; r < 4; ++r) {
          float p = __expf(s[nt][r]);
          lrow[mt][r] += p;
          int row = quad * 4 + r;
          int ch = nt * 2 + (c16 >> 3);
          Pt[wave][row][((ch ^ (row & 7)) * 8) + (c16 & 7)] = (short)f2bf(p);
        }
#pragma unroll
      for (int ks2 = 0; ks2 < 2; ++ks2) {
        short8 pf = *(const short8*)&Pt[wave][c16][(((ks2 * 4 + quad) ^ (c16 & 7)) & 7) * 8];
#pragma unroll
        for (int nt = 0; nt < 4; ++nt)
          accO[mt][nt] = __builtin_amdgcn_mfma_f32_16x16x32_bf16(pf, vbreg[ks2][nt], accO[mt][nt], 0, 0, 0);
      }
    }
    __syncthreads();  // drains next-tile DMA; protects buffer reuse
  }

  // one deferred l-reduction across the 16 c16 lanes
#pragma unroll
  for (int d = 1; d < 16; d <<= 1)
#pragma unroll
    for (int mt = 0; mt < 2; ++mt)
#pragma unroll
      for (int r = 0; r < 4; ++r) lrow[mt][r] += __shfl_xor(lrow[mt][r], d, 64);

#pragma unroll
  for (int mt = 0; mt < 2; ++mt)
#pragma unroll
    for (int nt = 0; nt < 4; ++nt)
#pragma unroll
      for (int r = 0; r < 4; ++r) {
        int qrow = qt * 128 + wave * 32 + mt * 16 + quad * 4 + r;
        O[((size_t)(b * SEQ + qrow)) * 1024 + h * 64 + nt * 16 + c16] =
            __float2bfloat16(accO[mt][nt][r] / lrow[mt][r]);
      }
#undef STAGE_K
#undef STAGE_V
}

extern "C" void kernel_launch(void* const* d_in, const int* in_sizes, int n_in,
                              void* d_out, int out_size, void* d_ws, size_t ws_size,
                              hipStream_t stream) {
  const void* q = d_in[0];
  const void* k = d_in[1];
  const void* v = d_in[2];
  const void* Wq = d_in[3];
  const void* bq = d_in[4];
  const void* Wk = d_in[5];
  const void* bk = d_in[6];
  const void* Wv = d_in[7];
  const void* bv = d_in[8];
  const void* Uq = d_in[9];
  const void* buq = d_in[10];
  const void* Uk = d_in[11];
  const void* buk = d_in[12];
  const void* pos = d_in[13];
  const void* th_cc = d_in[14];
  const void* th_co = d_in[15];
  const void* th_oc = d_in[16];
  const void* Wo = d_in[17];
  const void* bo = d_in[18];

  const int M = BS;  // 4096
  const size_t DD = (size_t)D_MODEL * D_MODEL;
  char* wsb = (char*)d_ws;
  int* flag = (int*)wsb;
  bf16* Qc = (bf16*)(wsb + 256);            // 8 MB
  bf16* Kc = Qc + (size_t)M * D_MODEL;      // 8 MB
  bf16* VcT = Kc + (size_t)M * D_MODEL;     // 8 MB, [D_MODEL][M]
  bf16* Qp = VcT + (size_t)M * D_MODEL;     // 2 MB
  bf16* Kp = Qp + (size_t)SEQ * D_MODEL;    // 2 MB
  u16* WT = (u16*)(Kp + (size_t)SEQ * D_MODEL);  // 6 x 2 MB
  bf16* AO = (bf16*)WT;  // aliases WqT..UqT (dead after g1); WoT (slot 5) untouched

  detect_kernel<<<1, 64, 0, stream>>>((const u16*)q, flag);

  dim3 blk(256);
  transpose_w<<<dim3(32, 32, 6), blk, 0, stream>>>(Wq, Wk, Wv, Uq, Uk, Wo, WT, flag);

  GArgs g1 = {{q, k, v, pos, pos},
              {WT + 0 * DD, WT + 1 * DD, WT + 2 * DD, WT + 3 * DD, WT + 4 * DD},
              {bq, bk, bv, buq, buk},
              {Qc, Kc, VcT, Qp, Kp},
              {M, M, M, SEQ, SEQ},
              {1, 1, 2, 1, 1}};
  gemm_mfma<1, 1><<<dim3(8, 32, 5), blk, 0, stream>>>(g1, flag);  // bf16-input twin
  gemm_mfma<0, 1><<<dim3(8, 32, 5), blk, 0, stream>>>(g1, flag);  // fp32-input twin

  flash_attn<<<dim3(NUM_HEADS, BATCH, SEQ / 128), blk, 0, stream>>>(
      Qc, Kc, VcT, Qp, Kp, th_cc, th_co, th_oc, AO, flag);

  GArgs g2 = {{AO, AO, AO, AO, AO},
              {WT + 5 * DD, WT + 5 * DD, WT + 5 * DD, WT + 5 * DD, WT + 5 * DD},
              {bo, bo, bo, bo, bo},
              {d_out, d_out, d_out, d_out, d_out},
              {M, M, M, M, M},
              {0, 0, 0, 0, 0}};
  gemm_mfma<1, 0><<<dim3(8, 32, 1), blk, 0, stream>>>(g2, flag);
}

// Round 11
// 285.807 us; speedup vs baseline: 1.1051x; 1.1051x over previous
//
#include <hip/hip_runtime.h>
#include <hip/hip_bf16.h>

typedef __hip_bfloat16 bf16;
typedef unsigned short u16;
typedef __attribute__((ext_vector_type(8))) short short8;
typedef __attribute__((ext_vector_type(4))) float f32x4;

#define D_MODEL 1024
#define NUM_HEADS 16
#define DEPTH 64
#define BATCH 4
#define SEQ 1024
#define BS (BATCH * SEQ)

__device__ __forceinline__ float ldDyn(const void* p, size_t i, int isbf) {
  return isbf ? __bfloat162float(((const bf16*)p)[i]) : ((const float*)p)[i];
}
__device__ __forceinline__ u16 f2bf(float f) {
  bf16 h = __float2bfloat16(f);
  return *(u16*)&h;
}
// async global->LDS, 16B per lane; LDS dest = wave-uniform base + lane*16
__device__ __forceinline__ void gl2lds16(const void* g, void* l) {
  __builtin_amdgcn_global_load_lds((const __attribute__((address_space(1))) unsigned int*)g,
                                   (__attribute__((address_space(3))) unsigned int*)l, 16, 0, 0);
}

// Detect input dtype: bf16 (1) vs fp32 (0). See round-1 notes.
__global__ void detect_kernel(const u16* __restrict__ q, int* __restrict__ flag) {
  if (threadIdx.x == 0 && blockIdx.x == 0) {
    int sane = 0;
    for (int i = 0; i < 64; ++i) {
      u16 h = q[2 * i];
      int e = (h >> 7) & 0xFF;
      if (e >= 100 && e <= 150) ++sane;
    }
    *flag = (sane >= 48) ? 1 : 0;
  }
}

// Batched 1024x1024 transpose (+convert to bf16): out[z][n][k] = in[z][k][n].
__global__ __launch_bounds__(256) void transpose_w(
    const void* W0, const void* W1, const void* W2, const void* W3, const void* W4,
    const void* W5, u16* __restrict__ WT, const int* __restrict__ flagp) {
  const int isbf = *flagp;
  const int z = blockIdx.z;
  const void* W = (z == 0) ? W0 : (z == 1) ? W1 : (z == 2) ? W2
                 : (z == 3) ? W3 : (z == 4) ? W4 : W5;
  u16* out = WT + (size_t)z * D_MODEL * D_MODEL;
  __shared__ u16 tile[32][33];
  const int t = threadIdx.x;
  const int tx = t & 31, ty = t >> 5;
  const int r0 = blockIdx.y * 32, c0 = blockIdx.x * 32;
#pragma unroll
  for (int i = 0; i < 4; ++i) {
    size_t gi = (size_t)(r0 + ty + 8 * i) * D_MODEL + c0 + tx;
    tile[ty + 8 * i][tx] = isbf ? ((const u16*)W)[gi] : f2bf(((const float*)W)[gi]);
  }
  __syncthreads();
#pragma unroll
  for (int i = 0; i < 4; ++i)
    out[(size_t)(c0 + ty + 8 * i) * D_MODEL + r0 + tx] = tile[tx][ty + 8 * i];
}

struct GArgs {
  const void* A[5];
  const u16* W[5];
  const void* bias[5];
  void* C[5];
  int Mr[5];
  int om[5];
};

// C(M,1024) = A(M,1024) @ W + bias, W passed transposed (WT, bf16).
// BK=64 variant: two BK=32 sub-tiles staged back-to-back, ONE barrier pair per
// 64 K. Halves the number of vmcnt(0) drains (the structural stall of this
// shape -- r10 showed dbuf is neutral, m99/m100-consistent) and doubles the
// MFMA work covered by each drain. LDS 32 KB -> still 5 blocks/CU.
// XCD swizzle keeps all col-blocks of an A row-panel on one XCD (r9: FETCH
// 218->68 MB). ABF: compile-time "A is bf16". GATE: early-exit unless runtime
// flag matches. omode: 0 = final out (dtype per flag); 1 = bf16; 2 = bf16
// transposed [N][M].
template <int ABF, int GATE>
__global__ __launch_bounds__(256) void gemm_mfma(GArgs ga, const int* __restrict__ flagp) {
  const int isbf = *flagp;
  if (GATE && isbf != ABF) return;
  const int z = blockIdx.z;
  const int M = ga.Mr[z];
  // XCD swizzle: grid (8,32,z). lin%8 == rowb%8 for every col-block of rowb.
  const int lin = blockIdx.x + 8 * blockIdx.y;  // 0..255
  const int xcd = lin & 7;
  const int loc = lin >> 3;                     // 0..31
  const int rowb = (loc & 3) * 8 + xcd;         // 0..31
  const int colb = loc >> 2;                    // 0..7
  const int row0 = rowb * 128, col0 = colb * 128;
  if (row0 >= M) return;
  const void* A = ga.A[z];
  const u16* WT = ga.W[z];
  const void* bias = ga.bias[z];
  void* C = ga.C[z];
  const int omode = ga.om[z];

  __shared__ short As[2][128][32];
  __shared__ short Bs[2][128][32];
  const int t = threadIdx.x;
  const int wave = t >> 6, lane = t & 63;
  const int quad = lane >> 4, c16 = lane & 15;
  const int wrow = wave >> 1, wcol = wave & 1;

  f32x4 acc[4][4];
#pragma unroll
  for (int mt = 0; mt < 4; ++mt)
#pragma unroll
    for (int nt = 0; nt < 4; ++nt) acc[mt][nt] = {0.f, 0.f, 0.f, 0.f};

#define G_STAGE(K0, BUF)                                                                  \
  {                                                                                       \
    _Pragma("unroll") for (int i = 0; i < 2; ++i) {                                       \
      int L = t + 256 * i;                                                                \
      int r = L >> 2;                                                                     \
      int kc = (L & 3) ^ (r & 3); /* swizzle on the global side; LDS dest linear */       \
      gl2lds16(WT + (size_t)(col0 + r) * 1024 + (K0) + kc * 8,                            \
               (char*)&Bs[BUF][0][0] + (size_t)(i * 256 + wave * 64) * 16);               \
      if (ABF) {                                                                          \
        gl2lds16((const u16*)A + (size_t)(row0 + r) * 1024 + (K0) + kc * 8,               \
                 (char*)&As[BUF][0][0] + (size_t)(i * 256 + wave * 64) * 16);             \
      } else {                                                                            \
        const float* af = (const float*)A + (size_t)(row0 + r) * 1024 + (K0) + kc * 8;    \
        float4 lo = *(const float4*)af;                                                   \
        float4 hi = *(const float4*)(af + 4);                                             \
        short8 v;                                                                         \
        u16* pv = (u16*)&v;                                                               \
        pv[0] = f2bf(lo.x); pv[1] = f2bf(lo.y); pv[2] = f2bf(lo.z); pv[3] = f2bf(lo.w);   \
        pv[4] = f2bf(hi.x); pv[5] = f2bf(hi.y); pv[6] = f2bf(hi.z); pv[7] = f2bf(hi.w);   \
        *(short8*)&As[BUF][r][(L & 3) * 8] = v;                                           \
      }                                                                                   \
    }                                                                                     \
  }

  for (int k0 = 0; k0 < 1024; k0 += 64) {
    G_STAGE(k0, 0);
    G_STAGE(k0 + 32, 1);
    __syncthreads();  // one drain per 64 K (two sub-tiles' DMA pipelined together)

#pragma unroll
    for (int h = 0; h < 2; ++h) {
      short8 af[4], bfv[4];
#pragma unroll
      for (int mt = 0; mt < 4; ++mt)
        af[mt] = *(const short8*)&As[h][wrow * 64 + mt * 16 + c16][((quad ^ (c16 & 3)) * 8)];
#pragma unroll
      for (int nt = 0; nt < 4; ++nt)
        bfv[nt] = *(const short8*)&Bs[h][wcol * 64 + nt * 16 + c16][((quad ^ (c16 & 3)) * 8)];
#pragma unroll
      for (int nt = 0; nt < 4; ++nt)
#pragma unroll
        for (int mt = 0; mt < 4; ++mt)
          acc[mt][nt] = __builtin_amdgcn_mfma_f32_16x16x32_bf16(af[mt], bfv[nt], acc[mt][nt], 0, 0, 0);
    }
    __syncthreads();
  }
#undef G_STAGE

#pragma unroll
  for (int nt = 0; nt < 4; ++nt) {
    int gc = col0 + wcol * 64 + nt * 16 + c16;
    float bb = ldDyn(bias, gc, isbf);
#pragma unroll
    for (int mt = 0; mt < 4; ++mt) {
      int gr0 = row0 + wrow * 64 + mt * 16 + quad * 4;
      if (omode == 2) {
        __attribute__((ext_vector_type(4))) short pk;
#pragma unroll
        for (int r = 0; r < 4; ++r) pk[r] = (short)f2bf(acc[mt][nt][r] + bb);
        *(__attribute__((ext_vector_type(4))) short*)&((u16*)C)[(size_t)gc * M + gr0] = pk;
      } else if (omode == 1 || isbf) {
#pragma unroll
        for (int r = 0; r < 4; ++r)
          ((bf16*)C)[(size_t)(gr0 + r) * 1024 + gc] = __float2bfloat16(acc[mt][nt][r] + bb);
      } else {
#pragma unroll
        for (int r = 0; r < 4; ++r)
          ((float*)C)[(size_t)(gr0 + r) * 1024 + gc] = acc[mt][nt][r] + bb;
      }
    }
  }
}

// Flash attention, m97-style: double-buffered async global_load_lds staging of
// the K-hat (64x128) and V^T (64x64) tiles; one barrier per kt drains the DMA.
// q-tile 128 (4 waves x 2 strips), K/V frags = swizzled ds_read_b128.
// Fixed-shift softmax (exact here); per-wave P roundtrip (8 KB).
__global__ __launch_bounds__(256) void flash_attn(
    const bf16* __restrict__ Qc, const bf16* __restrict__ Kc, const bf16* __restrict__ VcT,
    const bf16* __restrict__ Qp, const bf16* __restrict__ Kp,
    const void* __restrict__ th_cc, const void* __restrict__ th_co,
    const void* __restrict__ th_oc, bf16* __restrict__ O, const int* __restrict__ flagp) {
  const int isbf = *flagp;
  const int h = blockIdx.x, b = blockIdx.y, qt = blockIdx.z;
  const int t = threadIdx.x, wave = t >> 6, lane = t & 63;
  const int quad = lane >> 4, c16 = lane & 15;

  __shared__ short Kt[2][64][128];  // [buf][key][aug dims], slot kc holds chunk kc^(key&15)
  __shared__ short Vt[2][64][64];   // [buf][d][keys], slot kc holds chunk kc^(d&7)
  __shared__ short Pt[4][16][64];   // per-wave P strip (mt-sequential), swizzled ^ (row&7)

  const float tcc = ldDyn(th_cc, h, isbf);
  const float tco = ldDyn(th_co, h, isbf);
  const float toc = ldDyn(th_oc, h, isbf);

  const bf16* kcb = Kc + (size_t)b * SEQ * 1024 + h * 64;
  const bf16* kpb = Kp + h * 64;
  const bf16* vtb = VcT + (size_t)(h * 64) * BS + (size_t)b * SEQ;

  // staging lane roles
  const int rwK = lane >> 4, kcK = lane & 15;  // K-hat: 4 rows/inst, 16 chunks/row
  const int rwV = lane >> 3, kcV = lane & 7;   // V^T : 8 rows/inst,  8 chunks/row

#define STAGE_K(KT2, BUF)                                                              \
  {                                                                                    \
    _Pragma("unroll") for (int i = 0; i < 4; ++i) {                                    \
      int r = wave * 16 + i * 4 + rwK;                                                 \
      int c = kcK ^ (r & 15);                                                          \
      int key = (KT2)*64 + r;                                                          \
      const bf16* src = (c < 8) ? kcb + (size_t)key * 1024 + c * 8                     \
                                : kpb + (size_t)key * 1024 + c * 8 - 64;               \
      gl2lds16(src, &Kt[BUF][wave * 16 + i * 4][0]);                                   \
    }                                                                                  \
  }
#define STAGE_V(KT2, BUF)                                                              \
  {                                                                                    \
    _Pragma("unroll") for (int j = 0; j < 2; ++j) {                                    \
      int d = wave * 16 + j * 8 + rwV;                                                 \
      int c = kcV ^ (d & 7);                                                           \
      gl2lds16(vtb + (size_t)d * BS + (KT2)*64 + c * 8, &Vt[BUF][wave * 16 + j * 8][0]); \
    }                                                                                  \
  }

  // Q A-frags (register-resident, 2 strips)
  short8 qf[2][4];
#pragma unroll
  for (int mt = 0; mt < 2; ++mt) {
    int qrow = qt * 128 + wave * 32 + mt * 16 + c16;
#pragma unroll
    for (int ks = 0; ks < 4; ++ks) {
      int d = ks * 32 + quad * 8;
      const bf16* src = (d < 64) ? Qc + ((size_t)(b * SEQ + qrow)) * 1024 + h * 64 + d
                                 : Qp + (size_t)qrow * 1024 + h * 64 + (d - 64);
      qf[mt][ks] = *(const short8*)src;
    }
    if (qrow == 0) {  // zero pos-half for q==0 (theta replaces pos there)
      qf[mt][2] = (short8)0;
      qf[mt][3] = (short8)0;
    }
  }

  f32x4 accO[2][4];
#pragma unroll
  for (int mt = 0; mt < 2; ++mt)
#pragma unroll
    for (int nt = 0; nt < 4; ++nt) accO[mt][nt] = {0.f, 0.f, 0.f, 0.f};
  float lrow[2][4] = {{0.f, 0.f, 0.f, 0.f}, {0.f, 0.f, 0.f, 0.f}};

  // prologue: stage tile 0, drain, zero key-0 pos-half (theta replaces it)
  STAGE_K(0, 0);
  STAGE_V(0, 0);
  __syncthreads();
  if (t < 8) *(short8*)&Kt[0][0][64 + t * 8] = (short8)0;  // row0 swizzle = identity
  __syncthreads();

  for (int kt = 0; kt < 16; ++kt) {
    const int cur = kt & 1, nxt = cur ^ 1;
    if (kt < 15) {
      STAGE_K(kt + 1, nxt);
      STAGE_V(kt + 1, nxt);
    }

    // ---- S = Q-hat (32x128) x K-hat^T from LDS ----
    f32x4 accS[2][4];
#pragma unroll
    for (int mt = 0; mt < 2; ++mt)
#pragma unroll
      for (int nt = 0; nt < 4; ++nt) accS[mt][nt] = {0.f, 0.f, 0.f, 0.f};
#pragma unroll
    for (int nt = 0; nt < 4; ++nt)
#pragma unroll
      for (int ks = 0; ks < 4; ++ks) {
        short8 kf = *(const short8*)&Kt[cur][nt * 16 + c16][((ks * 4 + quad) ^ c16) * 8];
#pragma unroll
        for (int mt = 0; mt < 2; ++mt)
          accS[mt][nt] = __builtin_amdgcn_mfma_f32_16x16x32_bf16(qf[mt][ks], kf, accS[mt][nt], 0, 0, 0);
      }

    // ---- V frags to registers (reused by both strips) ----
    short8 vbreg[2][4];
#pragma unroll
    for (int ks2 = 0; ks2 < 2; ++ks2)
#pragma unroll
      for (int nt = 0; nt < 4; ++nt)
        vbreg[ks2][nt] =
            *(const short8*)&Vt[cur][nt * 16 + c16][(((ks2 * 4 + quad) ^ (c16 & 7)) & 7) * 8];

    // ---- per strip: softmax-lite + P roundtrip + PV ----
#pragma unroll
    for (int mt = 0; mt < 2; ++mt) {
      float s[4][4];
#pragma unroll
      for (int nt = 0; nt < 4; ++nt)
#pragma unroll
        for (int r = 0; r < 4; ++r) s[nt][r] = accS[mt][nt][r] * 0.125f;

      if (kt == 0 || (qt == 0 && wave == 0 && mt == 0)) {
#pragma unroll
        for (int nt = 0; nt < 4; ++nt)
#pragma unroll
          for (int r = 0; r < 4; ++r) {
            int kcol = kt * 64 + nt * 16 + c16;
            int qrow = qt * 128 + wave * 32 + mt * 16 + quad * 4 + r;
            float add = 0.f;
            if (qrow == 0 && kcol == 0) add = tcc;
            else if (qrow == 0) add = tco;
            else if (kcol == 0) add = toc;
            s[nt][r] += add * 0.125f;
          }
      }
#pragma unroll
      for (int nt = 0; nt < 4; ++nt)
#pragma unroll
        for (int r = 0; r < 4; ++r) {
          float p = __expf(s[nt][r]);
          lrow[mt][r] += p;
          int row = quad * 4 + r;
          int ch = nt * 2 + (c16 >> 3);
          Pt[wave][row][((ch ^ (row & 7)) * 8) + (c16 & 7)] = (short)f2bf(p);
        }
#pragma unroll
      for (int ks2 = 0; ks2 < 2; ++ks2) {
        short8 pf = *(const short8*)&Pt[wave][c16][(((ks2 * 4 + quad) ^ (c16 & 7)) & 7) * 8];
#pragma unroll
        for (int nt = 0; nt < 4; ++nt)
          accO[mt][nt] = __builtin_amdgcn_mfma_f32_16x16x32_bf16(pf, vbreg[ks2][nt], accO[mt][nt], 0, 0, 0);
      }
    }
    __syncthreads();  // drains next-tile DMA; protects buffer reuse
  }

  // one deferred l-reduction across the 16 c16 lanes
#pragma unroll
  for (int d = 1; d < 16; d <<= 1)
#pragma unroll
    for (int mt = 0; mt < 2; ++mt)
#pragma unroll
      for (int r = 0; r < 4; ++r) lrow[mt][r] += __shfl_xor(lrow[mt][r], d, 64);

#pragma unroll
  for (int mt = 0; mt < 2; ++mt)
#pragma unroll
    for (int nt = 0; nt < 4; ++nt)
#pragma unroll
      for (int r = 0; r < 4; ++r) {
        int qrow = qt * 128 + wave * 32 + mt * 16 + quad * 4 + r;
        O[((size_t)(b * SEQ + qrow)) * 1024 + h * 64 + nt * 16 + c16] =
            __float2bfloat16(accO[mt][nt][r] / lrow[mt][r]);
      }
#undef STAGE_K
#undef STAGE_V
}

extern "C" void kernel_launch(void* const* d_in, const int* in_sizes, int n_in,
                              void* d_out, int out_size, void* d_ws, size_t ws_size,
                              hipStream_t stream) {
  const void* q = d_in[0];
  const void* k = d_in[1];
  const void* v = d_in[2];
  const void* Wq = d_in[3];
  const void* bq = d_in[4];
  const void* Wk = d_in[5];
  const void* bk = d_in[6];
  const void* Wv = d_in[7];
  const void* bv = d_in[8];
  const void* Uq = d_in[9];
  const void* buq = d_in[10];
  const void* Uk = d_in[11];
  const void* buk = d_in[12];
  const void* pos = d_in[13];
  const void* th_cc = d_in[14];
  const void* th_co = d_in[15];
  const void* th_oc = d_in[16];
  const void* Wo = d_in[17];
  const void* bo = d_in[18];

  const int M = BS;  // 4096
  const size_t DD = (size_t)D_MODEL * D_MODEL;
  char* wsb = (char*)d_ws;
  int* flag = (int*)wsb;
  bf16* Qc = (bf16*)(wsb + 256);            // 8 MB
  bf16* Kc = Qc + (size_t)M * D_MODEL;      // 8 MB
  bf16* VcT = Kc + (size_t)M * D_MODEL;     // 8 MB, [D_MODEL][M]
  bf16* Qp = VcT + (size_t)M * D_MODEL;     // 2 MB
  bf16* Kp = Qp + (size_t)SEQ * D_MODEL;    // 2 MB
  u16* WT = (u16*)(Kp + (size_t)SEQ * D_MODEL);  // 6 x 2 MB
  bf16* AO = (bf16*)WT;  // aliases WqT..UqT (dead after g1); WoT (slot 5) untouched

  detect_kernel<<<1, 64, 0, stream>>>((const u16*)q, flag);

  dim3 blk(256);
  transpose_w<<<dim3(32, 32, 6), blk, 0, stream>>>(Wq, Wk, Wv, Uq, Uk, Wo, WT, flag);

  GArgs g1 = {{q, k, v, pos, pos},
              {WT + 0 * DD, WT + 1 * DD, WT + 2 * DD, WT + 3 * DD, WT + 4 * DD},
              {bq, bk, bv, buq, buk},
              {Qc, Kc, VcT, Qp, Kp},
              {M, M, M, SEQ, SEQ},
              {1, 1, 2, 1, 1}};
  gemm_mfma<1, 1><<<dim3(8, 32, 5), blk, 0, stream>>>(g1, flag);  // bf16-input twin
  gemm_mfma<0, 1><<<dim3(8, 32, 5), blk, 0, stream>>>(g1, flag);  // fp32-input twin

  flash_attn<<<dim3(NUM_HEADS, BATCH, SEQ / 128), blk, 0, stream>>>(
      Qc, Kc, VcT, Qp, Kp, th_cc, th_co, th_oc, AO, flag);

  GArgs g2 = {{AO, AO, AO, AO, AO},
              {WT + 5 * DD, WT + 5 * DD, WT + 5 * DD, WT + 5 * DD, WT + 5 * DD},
              {bo, bo, bo, bo, bo},
              {d_out, d_out, d_out, d_out, d_out},
              {M, M, M, M, M},
              {0, 0, 0, 0, 0}};
  gemm_mfma<1, 0><<<dim3(8, 32, 1), blk, 0, stream>>>(g2, flag);
}